// Round 7
// baseline (49.493 us; speedup 1.0000x reference)
//
#include <hip/hip_runtime.h>
#include <hip/hip_bf16.h>
#include <math.h>

typedef __attribute__((ext_vector_type(8))) short short8;
typedef __attribute__((ext_vector_type(4))) float f32x4;

namespace {
constexpr int BS    = 4;
constexpr int LSZ   = 256;
constexpr int CROPD = 246;
constexpr int NPTS  = BS * LSZ * LSZ;      // 262144
constexpr int NCROP = BS * CROPD * CROPD;  // 242064

constexpr int SZ_OMSI   = BS * 4 * CROPD * CROPD;
constexpr int SZ_OOFF   = BS * CROPD * CROPD * 2;
constexpr int SZ_PREMSI = BS * CROPD * CROPD;
constexpr int SZ_PREPAN = BS * CROPD * CROPD;
constexpr int SZ_OFFSET = NPTS * 2;
constexpr int SZ_SPEKC  = BS * CROPD * CROPD * 5;

constexpr int OFF_OMSI   = 0;
constexpr int OFF_OOFF   = OFF_OMSI + SZ_OMSI;
constexpr int OFF_PREMSI = OFF_OOFF + SZ_OOFF;
constexpr int OFF_PREPAN = OFF_PREMSI + SZ_PREMSI;
constexpr int OFF_OFFSET = OFF_PREPAN + SZ_PREPAN;
constexpr int OFF_SPEKC  = OFF_OFFSET + SZ_OFFSET;
constexpr int OFF_SPAK   = OFF_SPEKC + SZ_SPEKC;

// d_ws dword layout (prep_kernel output):
constexpr int WS_W2F   = 0;     // 7168 dw : w2 B-fragments (bf16 pairs)
constexpr int WS_HBF   = 7168;  //  512 dw : head B-fragments (bf16 pairs)
constexpr int WS_W1P   = 7680;  //  224 dw : (w1a,w1b) bf16 pairs, [kt][q][8]
constexpr int WS_B1T   = 7904;  //  224 dw : b1 f32, [kt][q][8]
constexpr int WS_B2V   = 8128;  //   64 dw : b2 padded to [4][16] f32
constexpr int WS_HBIAS = 8192;  //   16 dw : head biases per out-slot
constexpr int WS_NDW   = 8208;
} // namespace

static __device__ __forceinline__ unsigned short bf16u(float x) {
    __hip_bfloat16 h = __float2bfloat16(x);
    return __builtin_bit_cast(unsigned short, h);
}
static __device__ __forceinline__ unsigned int pk2(float a, float b) {
    return (unsigned int)bf16u(a) | ((unsigned int)bf16u(b) << 16);
}

// ---------------- prep: pack all weights into d_ws (runs every call) -------
__global__ __launch_bounds__(256) void prep_kernel(
    const float* __restrict__ w1, const float* __restrict__ b1,
    const float* __restrict__ w2, const float* __restrict__ b2,
    const float* __restrict__ wo, const float* __restrict__ bo,
    const float* __restrict__ wse, const float* __restrict__ bse,
    const float* __restrict__ wsa, const float* __restrict__ bsa,
    unsigned int* __restrict__ ws)
{
    const int d = blockIdx.x * 256 + threadIdx.x;
    if (d < 7168) {                       // W2F
        const int pi = d >> 8, rem = d & 255, lane = rem >> 2, jj = rem & 3;
        const int kt = pi >> 2, nt = pi & 3, q = lane >> 4, m = lane & 15;
        const int r0 = kt * 32 + q * 8 + 2 * jj, col = nt * 16 + m;
        const float v0 = (col < 50 && r0     < 200) ? w2[r0 * 50 + col]       : 0.f;
        const float v1 = (col < 50 && r0 + 1 < 200) ? w2[(r0 + 1) * 50 + col] : 0.f;
        ws[d] = pk2(v0, v1);
    } else if (d < 7680) {                // HBF
        const int e = d - 7168;
        const int kt2 = e >> 8, rem = e & 255, lane = rem >> 2, jj = rem & 3;
        const int q = lane >> 4, m = lane & 15;
        float v[2];
#pragma unroll
        for (int hlf = 0; hlf < 2; ++hlf) {
            const int f = kt2 * 32 + q * 8 + 2 * jj + hlf;
            float val = 0.f;
            if (f < 50 && m < 11) {
                if      (m < 2) val = wo [f * 2 + m];
                else if (m < 7) val = wse[f * 5 + (m - 2)];
                else            val = wsa[f * 4 + (m - 7)];
            }
            v[hlf] = val;
        }
        ws[d] = pk2(v[0], v[1]);
    } else if (d < 7904) {                // W1P
        const int e = d - 7680;
        const int kt = e >> 5, q = (e >> 3) & 3, j = e & 7;
        const int k = kt * 32 + q * 8 + j;
        const float a = (k < 200) ? w1[k]       : 0.f;
        const float b = (k < 200) ? w1[200 + k] : 0.f;
        ws[d] = pk2(a, b);
    } else if (d < 8128) {                // B1T (f32)
        const int e = d - 7904;
        const int kt = e >> 5, q = (e >> 3) & 3, j = e & 7;
        const int k = kt * 32 + q * 8 + j;
        ws[d] = __float_as_uint((k < 200) ? b1[k] : 0.f);
    } else if (d < 8192) {                // B2V
        const int e = d - 8128;
        const int f = (e >> 4) * 16 + (e & 15);
        ws[d] = __float_as_uint((f < 50) ? b2[f] : 0.f);
    } else if (d < WS_NDW) {              // HBIAS
        const int m = d - 8192;
        const float v = (m < 2) ? bo[m] : (m < 7) ? bse[m - 2] : (m < 11) ? bsa[m - 7] : 0.f;
        ws[d] = __float_as_uint(v);
    }
}

// ---------------- fused kernel: MLP (MFMA) + conv + grid-sample ------------
// R7: conv pan reads vectorized (rows are 15 contiguous floats -> 4x float4,
// 8B-aligned since col base 4w-6 is even). Cuts L1 line-transactions/wave
// ~3.8x vs scalar taps (the R6 stall: 64 lanes at 16B stride per scalar tap
// touched ~17 lines for 256B useful).
__global__ __launch_bounds__(256, 3) void fused_kernel(
    const float* __restrict__ coords,
    const unsigned int* __restrict__ ws,
    const float* __restrict__ pan,
    const float* __restrict__ msi,
    float* __restrict__ out)
{
    __shared__ __align__(16) unsigned short s_w2f[7168 * 2];   // 28672 B
    __shared__ __align__(16) unsigned short s_hbf[512 * 2];    //  2048 B
    __shared__ __align__(16) unsigned char  s_wbuf[4][5632];   // 22528 B
    // per-wave buf: [0,2304) f2 bf16 tile (16x72); [2304,5632) xfer 64x13 f32

    const int tid  = threadIdx.x;
    const int lane = tid & 63;
    const int wv   = tid >> 6;
    const int q    = lane >> 4;
    const int m    = lane & 15;
    const float* wsf = reinterpret_cast<const float*>(ws);

    const int pb0 = (blockIdx.x * 4 + wv) * 64;   // 1024 blocks

    // coords early (HBM latency hidden under staging)
    float2 cc[4];
#pragma unroll
    for (int t = 0; t < 4; ++t)
        cc[t] = reinterpret_cast<const float2*>(coords)[pb0 + t * 16 + m];

    // stage W2F + HBF into LDS
    {
        const uint4* __restrict__ g4 = reinterpret_cast<const uint4*>(ws);
        uint4* __restrict__ s4 = reinterpret_cast<uint4*>(s_w2f);
#pragma unroll
        for (int i = 0; i < 7; ++i) s4[tid + i * 256] = g4[tid + i * 256];
        if (tid < 128)
            reinterpret_cast<uint4*>(s_hbf)[tid] =
                reinterpret_cast<const uint4*>(ws + WS_HBF)[tid];
    }
    __syncthreads();

    // ---- layer 1 + main GEMM, interleaved per kt (low register pressure) --
    f32x4 acc[4][4];
#pragma unroll
    for (int t = 0; t < 4; ++t)
#pragma unroll
        for (int nt = 0; nt < 4; ++nt) acc[t][nt] = (f32x4){0, 0, 0, 0};

#pragma unroll
    for (int kt = 0; kt < 7; ++kt) {
        const uint4 u0 = *reinterpret_cast<const uint4*>(ws + WS_W1P + kt * 32 + q * 8);
        const uint4 u1 = *reinterpret_cast<const uint4*>(ws + WS_W1P + kt * 32 + q * 8 + 4);
        const float4 bb0 = *reinterpret_cast<const float4*>(wsf + WS_B1T + kt * 32 + q * 8);
        const float4 bb1 = *reinterpret_cast<const float4*>(wsf + WS_B1T + kt * 32 + q * 8 + 4);
        const unsigned int uu[8] = {u0.x, u0.y, u0.z, u0.w, u1.x, u1.y, u1.z, u1.w};
        const float bb[8] = {bb0.x, bb0.y, bb0.z, bb0.w, bb1.x, bb1.y, bb1.z, bb1.w};

        short8 A[4];
#pragma unroll
        for (int t = 0; t < 4; ++t) {
            float h[8];
#pragma unroll
            for (int j = 0; j < 8; ++j) {
                const float wa = __uint_as_float(uu[j] << 16);
                const float wb = __uint_as_float(uu[j] & 0xffff0000u);
                h[j] = fmaxf(fmaf(cc[t].x, wa, fmaf(cc[t].y, wb, bb[j])), 0.f);
            }
            union { unsigned int u[4]; short8 s; } af;
#pragma unroll
            for (int jj = 0; jj < 4; ++jj) af.u[jj] = pk2(h[2 * jj], h[2 * jj + 1]);
            A[t] = af.s;
        }
#pragma unroll
        for (int nt = 0; nt < 4; ++nt) {
            const short8 Bf = *reinterpret_cast<const short8*>(&s_w2f[((kt * 4 + nt) * 64 + lane) * 8]);
#pragma unroll
            for (int t = 0; t < 4; ++t)
                acc[t][nt] = __builtin_amdgcn_mfma_f32_16x16x32_bf16(A[t], Bf, acc[t][nt], 0, 0, 0);
        }
    }

    // ---- heads + output scatter + xfer redistribution, per tile ----------
    const float hbias = wsf[WS_HBIAS + m];
    float b2v[4];
#pragma unroll
    for (int nt = 0; nt < 4; ++nt) b2v[nt] = wsf[WS_B2V + nt * 16 + m];
    const short8 hB0 = *reinterpret_cast<const short8*>(&s_hbf[(0 * 64 + lane) * 8]);
    const short8 hB1 = *reinterpret_cast<const short8*>(&s_hbf[(1 * 64 + lane) * 8]);

    unsigned short* f2b = reinterpret_cast<unsigned short*>(&s_wbuf[wv][0]);
    float* xfer = reinterpret_cast<float*>(&s_wbuf[wv][2304]);

#pragma unroll
    for (int t = 0; t < 4; ++t) {
#pragma unroll
        for (int nt = 0; nt < 4; ++nt)
#pragma unroll
            for (int r = 0; r < 4; ++r)
                f2b[(q * 4 + r) * 72 + nt * 16 + m] =
                    bf16u(fmaxf(acc[t][nt][r] + b2v[nt], 0.f));
        asm volatile("s_waitcnt lgkmcnt(0)" ::: "memory");
        __builtin_amdgcn_sched_barrier(0);

        const short8 Af0 = *reinterpret_cast<const short8*>(&f2b[m * 72 +  0 + q * 8]);
        const short8 Af1 = *reinterpret_cast<const short8*>(&f2b[m * 72 + 32 + q * 8]);
        f32x4 h4 = {0, 0, 0, 0};
        h4 = __builtin_amdgcn_mfma_f32_16x16x32_bf16(Af0, hB0, h4, 0, 0, 0);
        h4 = __builtin_amdgcn_mfma_f32_16x16x32_bf16(Af1, hB1, h4, 0, 0, 0);
        asm volatile("s_waitcnt lgkmcnt(0)" ::: "memory");  // Af reads drained
        __builtin_amdgcn_sched_barrier(0);

        const int pbase = pb0 + t * 16;
#pragma unroll
        for (int r = 0; r < 4; ++r) {
            const float v = h4[r] + hbias;
            const int n = pbase + q * 4 + r;
            if (m < 11) xfer[(t * 16 + q * 4 + r) * 13 + m] = v;
            if (m < 2) {
                out[OFF_OFFSET + 2 * n + m] = v;
            } else if (m < 7) {
                const int b = n >> 16;
                const int h = (n >> 8) & 255;
                const int w = n & 255;
                if (h >= 5 && h < 251 && w >= 5 && w < 251)
                    out[OFF_SPEKC + (((b * CROPD) + (h - 5)) * CROPD + (w - 5)) * 5 + (m - 2)] = v;
            } else if (m < 11) {
                out[OFF_SPAK + 4 * n + (m - 7)] = v;
            }
        }
    }
    asm volatile("s_waitcnt lgkmcnt(0)" ::: "memory");
    __builtin_amdgcn_sched_barrier(0);

    // ---- bc phase: lane i handles point pb0+i ------------------------------
    float xv[11];
#pragma unroll
    for (int s = 0; s < 11; ++s) xv[s] = xfer[lane * 13 + s];

    const int n = pb0 + lane;
    const int b = n >> 16;
    const int h = (n >> 8) & 255;
    const int w = n & 255;
    if (h >= 5 && h < 251 && w >= 5 && w < 251) {
        const int hh = h - 5, ww = w - 5;
        const int tc = ((b * CROPD) + hh) * CROPD + ww;

        const float off0 = xv[0], off1 = xv[1];
        out[OFF_OOFF + 2 * tc + 0] = off0;
        out[OFF_OOFF + 2 * tc + 1] = off1;

        // grid-sample setup (gathers issued early)
        const float gx = fmaf((float)w, 2.0f / 255.0f, -1.0f) + off0 * (1.0f / 128.0f);
        const float gy = fmaf((float)h, 2.0f / 255.0f, -1.0f) + off1 * (1.0f / 128.0f);
        const float px = (gx + 1.0f) * 0.5f * 255.0f;
        const float py = (gy + 1.0f) * 0.5f * 255.0f;
        const float x0f = floorf(px), y0f = floorf(py);
        const float wx1 = px - x0f,  wy1 = py - y0f;
        const int x0 = (int)x0f, y0 = (int)y0f;
        const int x1 = x0 + 1,  y1 = y0 + 1;
        const bool vx0 = (x0 >= 0) & (x0 < 256);
        const bool vx1 = (x1 >= 0) & (x1 < 256);
        const bool vy0 = (y0 >= 0) & (y0 < 256);
        const bool vy1 = (y1 >= 0) & (y1 < 256);
        const int cx0 = min(max(x0, 0), 255), cx1 = min(max(x1, 0), 255);
        const int cy0 = min(max(y0, 0), 255), cy1 = min(max(y1, 0), 255);
        const float w00 = (1.0f - wy1) * (1.0f - wx1) * (float)(vy0 & vx0);
        const float w01 = (1.0f - wy1) * wx1          * (float)(vy0 & vx1);
        const float w10 = wy1 * (1.0f - wx1)          * (float)(vy1 & vx0);
        const float w11 = wy1 * wx1                   * (float)(vy1 & vx1);
        const int i00 = cy0 * 256 + cx0;
        const int i01 = cy0 * 256 + cx1;
        const int i10 = cy1 * 256 + cx0;
        const int i11 = cy1 * 256 + cx1;
        const float* mb = msi + ((size_t)b * 4) * 65536;
        float m00[4], m01[4], m10[4], m11[4];
#pragma unroll
        for (int ch = 0; ch < 4; ++ch) {
            const float* mc = mb + ch * 65536;
            m00[ch] = mc[i00]; m01[ch] = mc[i01]; m10[ch] = mc[i10]; m11[ch] = mc[i11];
        }

        // spatially-variant conv, central symmetry kv(p,q)=kv(14-p,14-q).
        // Row = 15 contiguous floats; load as 4x float4 (16th unused).
        const float a = xv[7], c = xv[9], d = xv[10];
        const float inv00 = a * a + c * c;
        const float inv01 = c * d;
        const float inv11 = d * d;
        const float* prow = pan + ((size_t)b << 20) + (size_t)(4 * h - 6) * 1024 + (4 * w - 6);

        float ksum = 1.0f;                       // center tap: kv = 1
        float conv;
        {
            union { float4 v[4]; float f[16]; } fr;
#pragma unroll
            for (int i = 0; i < 4; ++i)
                fr.v[i] = *reinterpret_cast<const float4*>(prow + 7 * 1024 + 4 * i);
            conv = fr.f[7];
#pragma unroll
            for (int qq = 0; qq < 7; ++qq) {     // row 7 pairs (gp = 0)
                const float gq = (float)(qq - 7);
                const float kv = __expf(-0.5f * inv11 * gq * gq);
                ksum += 2.0f * kv;
                conv = fmaf(kv, fr.f[qq] + fr.f[14 - qq], conv);
            }
        }
#pragma unroll
        for (int p = 0; p < 7; ++p) {            // rows p & 14-p
            union { float4 v[4]; float f[16]; } fa, fc;
#pragma unroll
            for (int i = 0; i < 4; ++i) {
                fa.v[i] = *reinterpret_cast<const float4*>(prow + p * 1024 + 4 * i);
                fc.v[i] = *reinterpret_cast<const float4*>(prow + (14 - p) * 1024 + 4 * i);
            }
            const float gp  = (float)(p - 7);
            const float tp  = inv00 * gp * gp;
            const float tpq = 2.0f * inv01 * gp;
#pragma unroll
            for (int qq = 0; qq < 15; ++qq) {
                const float gq = (float)(qq - 7);
                const float tt = fmaf(inv11 * gq, gq, fmaf(tpq, gq, tp));
                const float kv = __expf(-0.5f * tt);
                ksum += 2.0f * kv;
                conv = fmaf(kv, fa.f[qq] + fc.f[14 - qq], conv);
            }
        }
        out[OFF_PREPAN + tc] = conv / ksum;

        // finish sample + pre_msi
        float pm = xv[6];                        // "ones" channel * spek_c[4]
#pragma unroll
        for (int ch = 0; ch < 4; ++ch) {
            const float v = w00 * m00[ch] + w01 * m01[ch] + w10 * m10[ch] + w11 * m11[ch];
            out[OFF_OMSI + (((b * 4) + ch) * CROPD + hh) * CROPD + ww] = v;
            pm = fmaf(v, xv[2 + ch], pm);
        }
        out[OFF_PREMSI + tc] = pm;
    }
}

extern "C" void kernel_launch(void* const* d_in, const int* in_sizes, int n_in,
                              void* d_out, int out_size, void* d_ws, size_t ws_size,
                              hipStream_t stream)
{
    const float* msi    = (const float*)d_in[0];
    const float* pan    = (const float*)d_in[1];
    const float* coords = (const float*)d_in[2];
    const float* w1  = (const float*)d_in[3];
    const float* b1  = (const float*)d_in[4];
    const float* w2  = (const float*)d_in[5];
    const float* b2  = (const float*)d_in[6];
    const float* wo  = (const float*)d_in[7];
    const float* bo  = (const float*)d_in[8];
    const float* wse = (const float*)d_in[9];
    const float* bse = (const float*)d_in[10];
    const float* wsa = (const float*)d_in[11];
    const float* bsa = (const float*)d_in[12];
    float* out = (float*)d_out;
    unsigned int* ws = (unsigned int*)d_ws;

    prep_kernel<<<(WS_NDW + 255) / 256, 256, 0, stream>>>(
        w1, b1, w2, b2, wo, bo, wse, bse, wsa, bsa, ws);
    fused_kernel<<<1024, 256, 0, stream>>>(coords, ws, pan, msi, out);
}

// Round 8
// 47.794 us; speedup vs baseline: 1.0355x; 1.0355x over previous
//
#include <hip/hip_runtime.h>
#include <hip/hip_bf16.h>
#include <math.h>

typedef __attribute__((ext_vector_type(8))) short short8;
typedef __attribute__((ext_vector_type(4))) float f32x4;

namespace {
constexpr int BS    = 4;
constexpr int LSZ   = 256;
constexpr int CROPD = 246;
constexpr int NPTS  = BS * LSZ * LSZ;      // 262144
constexpr int NCROP = BS * CROPD * CROPD;  // 242064

constexpr int SZ_OMSI   = BS * 4 * CROPD * CROPD;
constexpr int SZ_OOFF   = BS * CROPD * CROPD * 2;
constexpr int SZ_PREMSI = BS * CROPD * CROPD;
constexpr int SZ_PREPAN = BS * CROPD * CROPD;
constexpr int SZ_OFFSET = NPTS * 2;
constexpr int SZ_SPEKC  = BS * CROPD * CROPD * 5;

constexpr int OFF_OMSI   = 0;
constexpr int OFF_OOFF   = OFF_OMSI + SZ_OMSI;
constexpr int OFF_PREMSI = OFF_OOFF + SZ_OOFF;
constexpr int OFF_PREPAN = OFF_PREMSI + SZ_PREMSI;
constexpr int OFF_OFFSET = OFF_PREPAN + SZ_PREPAN;
constexpr int OFF_SPEKC  = OFF_OFFSET + SZ_OFFSET;
constexpr int OFF_SPAK   = OFF_SPEKC + SZ_SPEKC;

// d_ws dword layout (prep_kernel output):
constexpr int WS_W2F   = 0;     // 7168 dw : w2 B-fragments (bf16 pairs)
constexpr int WS_HBF   = 7168;  //  512 dw : head B-fragments (bf16 pairs)
constexpr int WS_W1P   = 7680;  //  224 dw : (w1a,w1b) bf16 pairs, [kt][q][8]
constexpr int WS_B1T   = 7904;  //  224 dw : b1 f32, [kt][q][8]
constexpr int WS_B2V   = 8128;  //   64 dw : b2 padded to [4][16] f32
constexpr int WS_HBIAS = 8192;  //   16 dw : head biases per out-slot
constexpr int WS_NDW   = 8208;
} // namespace

static __device__ __forceinline__ unsigned short bf16u(float x) {
    __hip_bfloat16 h = __float2bfloat16(x);
    return __builtin_bit_cast(unsigned short, h);
}
static __device__ __forceinline__ unsigned int pk2(float a, float b) {
    return (unsigned int)bf16u(a) | ((unsigned int)bf16u(b) << 16);
}

// ---------------- prep: pack all weights into d_ws (runs every call) -------
__global__ __launch_bounds__(256) void prep_kernel(
    const float* __restrict__ w1, const float* __restrict__ b1,
    const float* __restrict__ w2, const float* __restrict__ b2,
    const float* __restrict__ wo, const float* __restrict__ bo,
    const float* __restrict__ wse, const float* __restrict__ bse,
    const float* __restrict__ wsa, const float* __restrict__ bsa,
    unsigned int* __restrict__ ws)
{
    const int d = blockIdx.x * 256 + threadIdx.x;
    if (d < 7168) {                       // W2F
        const int pi = d >> 8, rem = d & 255, lane = rem >> 2, jj = rem & 3;
        const int kt = pi >> 2, nt = pi & 3, q = lane >> 4, m = lane & 15;
        const int r0 = kt * 32 + q * 8 + 2 * jj, col = nt * 16 + m;
        const float v0 = (col < 50 && r0     < 200) ? w2[r0 * 50 + col]       : 0.f;
        const float v1 = (col < 50 && r0 + 1 < 200) ? w2[(r0 + 1) * 50 + col] : 0.f;
        ws[d] = pk2(v0, v1);
    } else if (d < 7680) {                // HBF
        const int e = d - 7168;
        const int kt2 = e >> 8, rem = e & 255, lane = rem >> 2, jj = rem & 3;
        const int q = lane >> 4, m = lane & 15;
        float v[2];
#pragma unroll
        for (int hlf = 0; hlf < 2; ++hlf) {
            const int f = kt2 * 32 + q * 8 + 2 * jj + hlf;
            float val = 0.f;
            if (f < 50 && m < 11) {
                if      (m < 2) val = wo [f * 2 + m];
                else if (m < 7) val = wse[f * 5 + (m - 2)];
                else            val = wsa[f * 4 + (m - 7)];
            }
            v[hlf] = val;
        }
        ws[d] = pk2(v[0], v[1]);
    } else if (d < 7904) {                // W1P
        const int e = d - 7680;
        const int kt = e >> 5, q = (e >> 3) & 3, j = e & 7;
        const int k = kt * 32 + q * 8 + j;
        const float a = (k < 200) ? w1[k]       : 0.f;
        const float b = (k < 200) ? w1[200 + k] : 0.f;
        ws[d] = pk2(a, b);
    } else if (d < 8128) {                // B1T (f32)
        const int e = d - 7904;
        const int kt = e >> 5, q = (e >> 3) & 3, j = e & 7;
        const int k = kt * 32 + q * 8 + j;
        ws[d] = __float_as_uint((k < 200) ? b1[k] : 0.f);
    } else if (d < 8192) {                // B2V
        const int e = d - 8128;
        const int f = (e >> 4) * 16 + (e & 15);
        ws[d] = __float_as_uint((f < 50) ? b2[f] : 0.f);
    } else if (d < WS_NDW) {              // HBIAS
        const int m = d - 8192;
        const float v = (m < 2) ? bo[m] : (m < 7) ? bse[m - 2] : (m < 11) ? bsa[m - 7] : 0.f;
        ws[d] = __float_as_uint(v);
    }
}

// ---------------- Kernel A: MFMA MLP, T=2 tiles/wave, 4 blocks/CU ----------
// LDS = 30720 (w2f+hbf blob) + 4*2304 (f2 tiles) = 39936 B -> exactly 4
// blocks/CU; whole 2048-block grid co-resident in one generation.
// No manual lgkmcnt/sched_barrier: DS ops are in-order per wave (WAR/RAW
// through LDS safe); compiler inserts minimal waits for register deps.
__global__ __launch_bounds__(256, 4) void mlp4(
    const float* __restrict__ coords,
    const unsigned int* __restrict__ ws,
    float* __restrict__ out)
{
    __shared__ __align__(16) unsigned int   s_wh[7680];        // 30720 B
    __shared__ __align__(16) unsigned short s_f2[4][16 * 72];  //  9216 B

    const int tid  = threadIdx.x;
    const int lane = tid & 63;
    const int wv   = tid >> 6;
    const int q    = lane >> 4;
    const int m    = lane & 15;
    const float* wsf = reinterpret_cast<const float*>(ws);

    const int pb0 = (blockIdx.x * 4 + wv) * 32;   // 2048 blocks, 2 tiles/wave

    // coords early (HBM latency hidden under staging)
    const float2 cA = reinterpret_cast<const float2*>(coords)[pb0 + m];
    const float2 cB = reinterpret_cast<const float2*>(coords)[pb0 + 16 + m];

    // stage W2F+HBF blob (contiguous 7680 dw) into LDS
    {
        const uint4* __restrict__ g4 = reinterpret_cast<const uint4*>(ws);
        uint4* __restrict__ s4 = reinterpret_cast<uint4*>(s_wh);
#pragma unroll
        for (int i = 0; i < 8; ++i) {
            const int idx = tid + i * 256;
            if (idx < 1920) s4[idx] = g4[idx];
        }
    }
    __syncthreads();

    // ---- layer 1 + main GEMM, interleaved per kt ----
    f32x4 acc0[4] = {{0,0,0,0},{0,0,0,0},{0,0,0,0},{0,0,0,0}};
    f32x4 acc1[4] = {{0,0,0,0},{0,0,0,0},{0,0,0,0},{0,0,0,0}};

#pragma unroll
    for (int kt = 0; kt < 7; ++kt) {
        const uint4 u0 = *reinterpret_cast<const uint4*>(ws + WS_W1P + kt * 32 + q * 8);
        const uint4 u1 = *reinterpret_cast<const uint4*>(ws + WS_W1P + kt * 32 + q * 8 + 4);
        const float4 bb0 = *reinterpret_cast<const float4*>(wsf + WS_B1T + kt * 32 + q * 8);
        const float4 bb1 = *reinterpret_cast<const float4*>(wsf + WS_B1T + kt * 32 + q * 8 + 4);
        const unsigned int uu[8] = {u0.x, u0.y, u0.z, u0.w, u1.x, u1.y, u1.z, u1.w};
        const float bb[8] = {bb0.x, bb0.y, bb0.z, bb0.w, bb1.x, bb1.y, bb1.z, bb1.w};

        float h0[8], h1[8];
#pragma unroll
        for (int j = 0; j < 8; ++j) {
            const float wa = __uint_as_float(uu[j] << 16);
            const float wb = __uint_as_float(uu[j] & 0xffff0000u);
            h0[j] = fmaxf(fmaf(cA.x, wa, fmaf(cA.y, wb, bb[j])), 0.f);
            h1[j] = fmaxf(fmaf(cB.x, wa, fmaf(cB.y, wb, bb[j])), 0.f);
        }
        union { unsigned int u[4]; short8 s; } a0, a1;
#pragma unroll
        for (int jj = 0; jj < 4; ++jj) {
            a0.u[jj] = pk2(h0[2 * jj], h0[2 * jj + 1]);
            a1.u[jj] = pk2(h1[2 * jj], h1[2 * jj + 1]);
        }
#pragma unroll
        for (int nt = 0; nt < 4; ++nt) {
            const short8 Bf = *reinterpret_cast<const short8*>(&s_wh[((kt * 4 + nt) * 64 + lane) * 4]);
            acc0[nt] = __builtin_amdgcn_mfma_f32_16x16x32_bf16(a0.s, Bf, acc0[nt], 0, 0, 0);
            acc1[nt] = __builtin_amdgcn_mfma_f32_16x16x32_bf16(a1.s, Bf, acc1[nt], 0, 0, 0);
        }
    }

    // ---- heads (per-wave f2 LDS transpose; compiler-scheduled waits) ----
    const float hbias = wsf[WS_HBIAS + m];
    float b2v[4];
#pragma unroll
    for (int nt = 0; nt < 4; ++nt) b2v[nt] = wsf[WS_B2V + nt * 16 + m];
    const short8 hB0 = *reinterpret_cast<const short8*>(&s_wh[(7168 + 0) + 0] + lane * 4);
    const short8 hB1 = *reinterpret_cast<const short8*>(&s_wh[7168 + 256] + lane * 4);

    unsigned short* f2b = s_f2[wv];

#pragma unroll
    for (int t = 0; t < 2; ++t) {
        const f32x4* acc = t ? acc1 : acc0;
#pragma unroll
        for (int nt = 0; nt < 4; ++nt)
#pragma unroll
            for (int r = 0; r < 4; ++r)
                f2b[(q * 4 + r) * 72 + nt * 16 + m] =
                    bf16u(fmaxf(acc[nt][r] + b2v[nt], 0.f));

        const short8 Af0 = *reinterpret_cast<const short8*>(&f2b[m * 72 +  0 + q * 8]);
        const short8 Af1 = *reinterpret_cast<const short8*>(&f2b[m * 72 + 32 + q * 8]);
        f32x4 h4 = {0, 0, 0, 0};
        h4 = __builtin_amdgcn_mfma_f32_16x16x32_bf16(Af0, hB0, h4, 0, 0, 0);
        h4 = __builtin_amdgcn_mfma_f32_16x16x32_bf16(Af1, hB1, h4, 0, 0, 0);

        const int pbase = pb0 + t * 16;
#pragma unroll
        for (int r = 0; r < 4; ++r) {
            const float v = h4[r] + hbias;
            const int n = pbase + q * 4 + r;
            if (m < 2) {
                out[OFF_OFFSET + 2 * n + m] = v;
            } else if (m < 7) {
                const int b = n >> 16;
                const int h = (n >> 8) & 255;
                const int w = n & 255;
                if (h >= 5 && h < 251 && w >= 5 && w < 251)
                    out[OFF_SPEKC + (((b * CROPD) + (h - 5)) * CROPD + (w - 5)) * 5 + (m - 2)] = v;
            } else if (m < 11) {
                out[OFF_SPAK + 4 * n + (m - 7)] = v;
            }
        }
    }
}

// ---------------- Kernel BC: conv + grid-sample (zero LDS, high occ) -------
__global__ __launch_bounds__(256) void bc_kernel(
    const float* __restrict__ pan,
    const float* __restrict__ msi,
    float* __restrict__ out)
{
    const int t = blockIdx.x * blockDim.x + threadIdx.x;
    if (t >= NCROP) return;

    const int b  = t / (CROPD * CROPD);
    const int r  = t % (CROPD * CROPD);
    const int hh = r / CROPD;
    const int ww = r % CROPD;
    const int h = hh + 5, w = ww + 5;
    const int n = (b << 16) + (h << 8) + w;

    const float off0 = out[OFF_OFFSET + 2 * n + 0];
    const float off1 = out[OFF_OFFSET + 2 * n + 1];
    out[OFF_OOFF + 2 * t + 0] = off0;
    out[OFF_OOFF + 2 * t + 1] = off1;

    const float* spak = out + OFF_SPAK;
    const float a = spak[4 * n + 0];
    const float c = spak[4 * n + 2];
    const float d = spak[4 * n + 3];
    const float inv00 = a * a + c * c;
    const float inv01 = c * d;
    const float inv11 = d * d;

    // grid-sample setup (gathers issued early)
    const float gx = fmaf((float)w, 2.0f / 255.0f, -1.0f) + off0 * (1.0f / 128.0f);
    const float gy = fmaf((float)h, 2.0f / 255.0f, -1.0f) + off1 * (1.0f / 128.0f);
    const float px = (gx + 1.0f) * 0.5f * 255.0f;
    const float py = (gy + 1.0f) * 0.5f * 255.0f;
    const float x0f = floorf(px), y0f = floorf(py);
    const float wx1 = px - x0f,  wy1 = py - y0f;
    const int x0 = (int)x0f, y0 = (int)y0f;
    const int x1 = x0 + 1,  y1 = y0 + 1;
    const bool vx0 = (x0 >= 0) & (x0 < 256);
    const bool vx1 = (x1 >= 0) & (x1 < 256);
    const bool vy0 = (y0 >= 0) & (y0 < 256);
    const bool vy1 = (y1 >= 0) & (y1 < 256);
    const int cx0 = min(max(x0, 0), 255), cx1 = min(max(x1, 0), 255);
    const int cy0 = min(max(y0, 0), 255), cy1 = min(max(y1, 0), 255);
    const float w00 = (1.0f - wy1) * (1.0f - wx1) * (float)(vy0 & vx0);
    const float w01 = (1.0f - wy1) * wx1          * (float)(vy0 & vx1);
    const float w10 = wy1 * (1.0f - wx1)          * (float)(vy1 & vx0);
    const float w11 = wy1 * wx1                   * (float)(vy1 & vx1);
    const int i00 = cy0 * 256 + cx0;
    const int i01 = cy0 * 256 + cx1;
    const int i10 = cy1 * 256 + cx0;
    const int i11 = cy1 * 256 + cx1;
    const float* mb = msi + ((size_t)b * 4) * 65536;
    float m00[4], m01[4], m10[4], m11[4];
#pragma unroll
    for (int ch = 0; ch < 4; ++ch) {
        const float* mc = mb + ch * 65536;
        m00[ch] = mc[i00]; m01[ch] = mc[i01]; m10[ch] = mc[i10]; m11[ch] = mc[i11];
    }

    // spatially-variant conv, central symmetry kv(p,q)=kv(14-p,14-q)
    const float* prow = pan + ((size_t)b << 20) + (size_t)(4 * h - 6) * 1024 + (4 * w - 6);
    float ksum = 1.0f;
    float conv = prow[7 * 1024 + 7];
#pragma unroll
    for (int qq = 0; qq < 7; ++qq) {             // row 7 pairs (gp = 0)
        const float gq = (float)(qq - 7);
        const float kv = __expf(-0.5f * inv11 * gq * gq);
        ksum += 2.0f * kv;
        conv = fmaf(kv, prow[7 * 1024 + qq] + prow[7 * 1024 + 14 - qq], conv);
    }
    for (int p = 0; p < 7; ++p) {                // rows p & 14-p
        const float gp  = (float)(p - 7);
        const float tp  = inv00 * gp * gp;
        const float tpq = 2.0f * inv01 * gp;
        const float* pa = prow + p * 1024;
        const float* pc = prow + (14 - p) * 1024;
#pragma unroll
        for (int qq = 0; qq < 15; ++qq) {
            const float gq = (float)(qq - 7);
            const float tt = fmaf(inv11 * gq, gq, fmaf(tpq, gq, tp));
            const float kv = __expf(-0.5f * tt);
            ksum += 2.0f * kv;
            conv = fmaf(kv, pa[qq] + pc[14 - qq], conv);
        }
    }
    out[OFF_PREPAN + t] = conv / ksum;

    // finish sample + pre_msi
    const float* spc = out + OFF_SPEKC + 5 * t;
    float pm = spc[4];
#pragma unroll
    for (int ch = 0; ch < 4; ++ch) {
        const float v = w00 * m00[ch] + w01 * m01[ch] + w10 * m10[ch] + w11 * m11[ch];
        out[OFF_OMSI + (((b * 4) + ch) * CROPD + hh) * CROPD + ww] = v;
        pm = fmaf(v, spc[ch], pm);
    }
    out[OFF_PREMSI + t] = pm;
}

extern "C" void kernel_launch(void* const* d_in, const int* in_sizes, int n_in,
                              void* d_out, int out_size, void* d_ws, size_t ws_size,
                              hipStream_t stream)
{
    const float* msi    = (const float*)d_in[0];
    const float* pan    = (const float*)d_in[1];
    const float* coords = (const float*)d_in[2];
    const float* w1  = (const float*)d_in[3];
    const float* b1  = (const float*)d_in[4];
    const float* w2  = (const float*)d_in[5];
    const float* b2  = (const float*)d_in[6];
    const float* wo  = (const float*)d_in[7];
    const float* bo  = (const float*)d_in[8];
    const float* wse = (const float*)d_in[9];
    const float* bse = (const float*)d_in[10];
    const float* wsa = (const float*)d_in[11];
    const float* bsa = (const float*)d_in[12];
    float* out = (float*)d_out;
    unsigned int* ws = (unsigned int*)d_ws;

    prep_kernel<<<(WS_NDW + 255) / 256, 256, 0, stream>>>(
        w1, b1, w2, b2, wo, bo, wse, bse, wsa, bsa, ws);
    mlp4<<<2048, 256, 0, stream>>>(coords, ws, out);
    const int gcrop = (NCROP + 255) / 256;
    bc_kernel<<<gcrop, 256, 0, stream>>>(pan, msi, out);
}

// Round 9
// 41.300 us; speedup vs baseline: 1.1984x; 1.1573x over previous
//
#include <hip/hip_runtime.h>
#include <hip/hip_bf16.h>
#include <math.h>

typedef __attribute__((ext_vector_type(8))) short short8;
typedef __attribute__((ext_vector_type(4))) float f32x4;

namespace {
constexpr int BS    = 4;
constexpr int LSZ   = 256;
constexpr int CROPD = 246;
constexpr int NPTS  = BS * LSZ * LSZ;      // 262144
constexpr int NCROP = BS * CROPD * CROPD;  // 242064

constexpr int SZ_OMSI   = BS * 4 * CROPD * CROPD;
constexpr int SZ_OOFF   = BS * CROPD * CROPD * 2;
constexpr int SZ_PREMSI = BS * CROPD * CROPD;
constexpr int SZ_PREPAN = BS * CROPD * CROPD;
constexpr int SZ_OFFSET = NPTS * 2;
constexpr int SZ_SPEKC  = BS * CROPD * CROPD * 5;

constexpr int OFF_OMSI   = 0;
constexpr int OFF_OOFF   = OFF_OMSI + SZ_OMSI;
constexpr int OFF_PREMSI = OFF_OOFF + SZ_OOFF;
constexpr int OFF_PREPAN = OFF_PREMSI + SZ_PREMSI;
constexpr int OFF_OFFSET = OFF_PREPAN + SZ_PREPAN;
constexpr int OFF_SPEKC  = OFF_OFFSET + SZ_OFFSET;
constexpr int OFF_SPAK   = OFF_SPEKC + SZ_SPEKC;

// d_ws dword layout (prep_kernel output):
constexpr int WS_W2F   = 0;     // 7168 dw : w2 B-fragments (bf16 pairs)
constexpr int WS_HBF   = 7168;  //  512 dw : head B-fragments (bf16 pairs)
constexpr int WS_W1P   = 7680;  //  224 dw : (w1a,w1b) bf16 pairs, [kt][q][8]
constexpr int WS_B1T   = 7904;  //  224 dw : b1 f32, [kt][q][8]
constexpr int WS_B2V   = 8128;  //   64 dw : b2 padded to [4][16] f32
constexpr int WS_HBIAS = 8192;  //   16 dw : head biases per out-slot
constexpr int WS_NDW   = 8208;
} // namespace

static __device__ __forceinline__ unsigned short bf16u(float x) {
    __hip_bfloat16 h = __float2bfloat16(x);
    return __builtin_bit_cast(unsigned short, h);
}
static __device__ __forceinline__ unsigned int pk2(float a, float b) {
    return (unsigned int)bf16u(a) | ((unsigned int)bf16u(b) << 16);
}

// ---------------- prep: pack all weights into d_ws (runs every call) -------
__global__ __launch_bounds__(256) void prep_kernel(
    const float* __restrict__ w1, const float* __restrict__ b1,
    const float* __restrict__ w2, const float* __restrict__ b2,
    const float* __restrict__ wo, const float* __restrict__ bo,
    const float* __restrict__ wse, const float* __restrict__ bse,
    const float* __restrict__ wsa, const float* __restrict__ bsa,
    unsigned int* __restrict__ ws)
{
    const int d = blockIdx.x * 256 + threadIdx.x;
    if (d < 7168) {                       // W2F
        const int pi = d >> 8, rem = d & 255, lane = rem >> 2, jj = rem & 3;
        const int kt = pi >> 2, nt = pi & 3, q = lane >> 4, m = lane & 15;
        const int r0 = kt * 32 + q * 8 + 2 * jj, col = nt * 16 + m;
        const float v0 = (col < 50 && r0     < 200) ? w2[r0 * 50 + col]       : 0.f;
        const float v1 = (col < 50 && r0 + 1 < 200) ? w2[(r0 + 1) * 50 + col] : 0.f;
        ws[d] = pk2(v0, v1);
    } else if (d < 7680) {                // HBF
        const int e = d - 7168;
        const int kt2 = e >> 8, rem = e & 255, lane = rem >> 2, jj = rem & 3;
        const int q = lane >> 4, m = lane & 15;
        float v[2];
#pragma unroll
        for (int hlf = 0; hlf < 2; ++hlf) {
            const int f = kt2 * 32 + q * 8 + 2 * jj + hlf;
            float val = 0.f;
            if (f < 50 && m < 11) {
                if      (m < 2) val = wo [f * 2 + m];
                else if (m < 7) val = wse[f * 5 + (m - 2)];
                else            val = wsa[f * 4 + (m - 7)];
            }
            v[hlf] = val;
        }
        ws[d] = pk2(v[0], v[1]);
    } else if (d < 7904) {                // W1P
        const int e = d - 7680;
        const int kt = e >> 5, q = (e >> 3) & 3, j = e & 7;
        const int k = kt * 32 + q * 8 + j;
        const float a = (k < 200) ? w1[k]       : 0.f;
        const float b = (k < 200) ? w1[200 + k] : 0.f;
        ws[d] = pk2(a, b);
    } else if (d < 8128) {                // B1T (f32)
        const int e = d - 7904;
        const int kt = e >> 5, q = (e >> 3) & 3, j = e & 7;
        const int k = kt * 32 + q * 8 + j;
        ws[d] = __float_as_uint((k < 200) ? b1[k] : 0.f);
    } else if (d < 8192) {                // B2V
        const int e = d - 8128;
        const int f = (e >> 4) * 16 + (e & 15);
        ws[d] = __float_as_uint((f < 50) ? b2[f] : 0.f);
    } else if (d < WS_NDW) {              // HBIAS
        const int m = d - 8192;
        const float v = (m < 2) ? bo[m] : (m < 7) ? bse[m - 2] : (m < 11) ? bsa[m - 7] : 0.f;
        ws[d] = __float_as_uint(v);
    }
}

// ---------------- fused: MLP (MFMA) + conv + grid-sample, SMALL CODE -------
// R9 theory: previous versions were instruction-fetch bound (~20KB straight-
// line bodies; 16 waves/CU at distinct PCs thrash the 32KB I-cache -> all
// exec pipes <30% despite ~12us pipe-sum). Fix: roll the kt loop and conv
// row loop (#pragma unroll 1); target <=8KB code. Also: 39936B LDS -> 4
// blocks/CU, all 1024 blocks co-resident; xfer deferred via ha[] regs so it
// reuses the f2 LDS region; no manual waitcnt (in-order DS per wave).
__global__ __launch_bounds__(256, 4) void fused_kernel(
    const float* __restrict__ coords,
    const unsigned int* __restrict__ ws,
    const float* __restrict__ pan,
    const float* __restrict__ msi,
    float* __restrict__ out)
{
    __shared__ __align__(16) unsigned int  s_w2f[7168];      // 28672 B
    __shared__ __align__(16) unsigned char s_buf[4][2816];   // 11264 B
    // per-wave s_buf: phase1 = f2 bf16 tile 16x72 (2304B); phase2 = xfer 64x11 f32 (2816B)

    const int tid  = threadIdx.x;
    const int lane = tid & 63;
    const int wv   = tid >> 6;
    const int q    = lane >> 4;
    const int m    = lane & 15;
    const float* wsf = reinterpret_cast<const float*>(ws);

    const int pb0 = (blockIdx.x * 4 + wv) * 64;   // 1024 blocks, 64 pts/wave

    float2 cc[4];
#pragma unroll
    for (int t = 0; t < 4; ++t)
        cc[t] = reinterpret_cast<const float2*>(coords)[pb0 + t * 16 + m];

    // stage W2F into LDS (7168 dw = 1792 uint4, exact)
    {
        const uint4* __restrict__ g4 = reinterpret_cast<const uint4*>(ws);
        uint4* __restrict__ s4 = reinterpret_cast<uint4*>(s_w2f);
#pragma unroll 1
        for (int i = 0; i < 7; ++i) s4[tid + i * 256] = g4[tid + i * 256];
    }
    __syncthreads();

    // ---- layer 1 + main GEMM, ROLLED kt loop ----
    f32x4 acc[4][4];
#pragma unroll
    for (int t = 0; t < 4; ++t)
#pragma unroll
        for (int nt = 0; nt < 4; ++nt) acc[t][nt] = (f32x4){0, 0, 0, 0};

#pragma unroll 1
    for (int kt = 0; kt < 7; ++kt) {
        const uint4 u0 = *reinterpret_cast<const uint4*>(ws + WS_W1P + kt * 32 + q * 8);
        const uint4 u1 = *reinterpret_cast<const uint4*>(ws + WS_W1P + kt * 32 + q * 8 + 4);
        const float4 bb0 = *reinterpret_cast<const float4*>(wsf + WS_B1T + kt * 32 + q * 8);
        const float4 bb1 = *reinterpret_cast<const float4*>(wsf + WS_B1T + kt * 32 + q * 8 + 4);
        const unsigned int uu[8] = {u0.x, u0.y, u0.z, u0.w, u1.x, u1.y, u1.z, u1.w};
        const float bb[8] = {bb0.x, bb0.y, bb0.z, bb0.w, bb1.x, bb1.y, bb1.z, bb1.w};

        short8 A[4];
#pragma unroll
        for (int t = 0; t < 4; ++t) {
            float h[8];
#pragma unroll
            for (int j = 0; j < 8; ++j) {
                const float wa = __uint_as_float(uu[j] << 16);
                const float wb = __uint_as_float(uu[j] & 0xffff0000u);
                h[j] = fmaxf(fmaf(cc[t].x, wa, fmaf(cc[t].y, wb, bb[j])), 0.f);
            }
            union { unsigned int u[4]; short8 s; } af;
#pragma unroll
            for (int jj = 0; jj < 4; ++jj) af.u[jj] = pk2(h[2 * jj], h[2 * jj + 1]);
            A[t] = af.s;
        }
#pragma unroll
        for (int nt = 0; nt < 4; ++nt) {
            const short8 Bf = *reinterpret_cast<const short8*>(&s_w2f[((kt * 4 + nt) * 64 + lane) * 4]);
#pragma unroll
            for (int t = 0; t < 4; ++t)
                acc[t][nt] = __builtin_amdgcn_mfma_f32_16x16x32_bf16(A[t], Bf, acc[t][nt], 0, 0, 0);
        }
    }

    // ---- heads (unrolled: acc needs static indexing) ----
    const float hbias = wsf[WS_HBIAS + m];
    float b2v[4];
#pragma unroll
    for (int nt = 0; nt < 4; ++nt) b2v[nt] = wsf[WS_B2V + nt * 16 + m];
    const short8 hB0 = *reinterpret_cast<const short8*>(ws + WS_HBF + lane * 4);
    const short8 hB1 = *reinterpret_cast<const short8*>(ws + WS_HBF + 256 + lane * 4);

    unsigned short* f2b = reinterpret_cast<unsigned short*>(&s_buf[wv][0]);
    f32x4 ha[4];

#pragma unroll
    for (int t = 0; t < 4; ++t) {
#pragma unroll
        for (int nt = 0; nt < 4; ++nt)
#pragma unroll
            for (int r = 0; r < 4; ++r)
                f2b[(q * 4 + r) * 72 + nt * 16 + m] =
                    bf16u(fmaxf(acc[t][nt][r] + b2v[nt], 0.f));

        const short8 Af0 = *reinterpret_cast<const short8*>(&f2b[m * 72 +  0 + q * 8]);
        const short8 Af1 = *reinterpret_cast<const short8*>(&f2b[m * 72 + 32 + q * 8]);
        f32x4 h4 = {0, 0, 0, 0};
        h4 = __builtin_amdgcn_mfma_f32_16x16x32_bf16(Af0, hB0, h4, 0, 0, 0);
        h4 = __builtin_amdgcn_mfma_f32_16x16x32_bf16(Af1, hB1, h4, 0, 0, 0);
        ha[t] = h4;

        const int pbase = pb0 + t * 16;
#pragma unroll
        for (int r = 0; r < 4; ++r) {
            const float v = h4[r] + hbias;
            const int n = pbase + q * 4 + r;
            if (m < 2) {
                out[OFF_OFFSET + 2 * n + m] = v;
            } else if (m < 7) {
                const int b = n >> 16;
                const int h = (n >> 8) & 255;
                const int w = n & 255;
                if (h >= 5 && h < 251 && w >= 5 && w < 251)
                    out[OFF_SPEKC + (((b * CROPD) + (h - 5)) * CROPD + (w - 5)) * 5 + (m - 2)] = v;
            } else if (m < 11) {
                out[OFF_SPAK + 4 * n + (m - 7)] = v;
            }
        }
    }

    // ---- xfer: redistribute 11 outs/point into per-wave LDS (f2 region dead)
    float* xfer = reinterpret_cast<float*>(&s_buf[wv][0]);
    if (m < 11) {
#pragma unroll
        for (int t = 0; t < 4; ++t)
#pragma unroll
            for (int r = 0; r < 4; ++r)
                xfer[(t * 16 + q * 4 + r) * 11 + m] = ha[t][r] + hbias;
    }

    // ---- bc phase: lane i handles point pb0+i ----
    float xv[11];
#pragma unroll
    for (int s = 0; s < 11; ++s) xv[s] = xfer[lane * 11 + s];

    const int n = pb0 + lane;
    const int b = n >> 16;
    const int h = (n >> 8) & 255;
    const int w = n & 255;
    if (h >= 5 && h < 251 && w >= 5 && w < 251) {
        const int hh = h - 5, ww = w - 5;
        const int tc = ((b * CROPD) + hh) * CROPD + ww;

        const float off0 = xv[0], off1 = xv[1];
        out[OFF_OOFF + 2 * tc + 0] = off0;
        out[OFF_OOFF + 2 * tc + 1] = off1;

        // grid-sample setup (gathers issued early)
        const float gx = fmaf((float)w, 2.0f / 255.0f, -1.0f) + off0 * (1.0f / 128.0f);
        const float gy = fmaf((float)h, 2.0f / 255.0f, -1.0f) + off1 * (1.0f / 128.0f);
        const float px = (gx + 1.0f) * 0.5f * 255.0f;
        const float py = (gy + 1.0f) * 0.5f * 255.0f;
        const float x0f = floorf(px), y0f = floorf(py);
        const float wx1 = px - x0f,  wy1 = py - y0f;
        const int x0 = (int)x0f, y0 = (int)y0f;
        const int x1 = x0 + 1,  y1 = y0 + 1;
        const bool vx0 = (x0 >= 0) & (x0 < 256);
        const bool vx1 = (x1 >= 0) & (x1 < 256);
        const bool vy0 = (y0 >= 0) & (y0 < 256);
        const bool vy1 = (y1 >= 0) & (y1 < 256);
        const int cx0 = min(max(x0, 0), 255), cx1 = min(max(x1, 0), 255);
        const int cy0 = min(max(y0, 0), 255), cy1 = min(max(y1, 0), 255);
        const float w00 = (1.0f - wy1) * (1.0f - wx1) * (float)(vy0 & vx0);
        const float w01 = (1.0f - wy1) * wx1          * (float)(vy0 & vx1);
        const float w10 = wy1 * (1.0f - wx1)          * (float)(vy1 & vx0);
        const float w11 = wy1 * wx1                   * (float)(vy1 & vx1);
        const int i00 = cy0 * 256 + cx0;
        const int i01 = cy0 * 256 + cx1;
        const int i10 = cy1 * 256 + cx0;
        const int i11 = cy1 * 256 + cx1;
        const float* mb = msi + ((size_t)b * 4) * 65536;
        float m00[4], m01[4], m10[4], m11[4];
#pragma unroll
        for (int ch = 0; ch < 4; ++ch) {
            const float* mc = mb + ch * 65536;
            m00[ch] = mc[i00]; m01[ch] = mc[i01]; m10[ch] = mc[i10]; m11[ch] = mc[i11];
        }

        // spatially-variant conv, central symmetry; ROLLED row loop
        const float a = xv[7], c = xv[9], d = xv[10];
        const float inv00 = a * a + c * c;
        const float inv01 = c * d;
        const float inv11 = d * d;
        const float* prow = pan + ((size_t)b << 20) + (size_t)(4 * h - 6) * 1024 + (4 * w - 6);

        float ksum = 1.0f;
        float conv = prow[7 * 1024 + 7];
#pragma unroll 1
        for (int qq = 0; qq < 7; ++qq) {         // row 7 pairs (gp = 0)
            const float gq = (float)(qq - 7);
            const float kv = __expf(-0.5f * inv11 * gq * gq);
            ksum += 2.0f * kv;
            conv = fmaf(kv, prow[7 * 1024 + qq] + prow[7 * 1024 + 14 - qq], conv);
        }
#pragma unroll 1
        for (int p = 0; p < 7; ++p) {            // rows p & 14-p
            const float gp  = (float)(p - 7);
            const float tp  = inv00 * gp * gp;
            const float tpq = 2.0f * inv01 * gp;
            const float* pa = prow + p * 1024;
            const float* pc = prow + (14 - p) * 1024;
#pragma unroll
            for (int qq = 0; qq < 15; ++qq) {
                const float gq = (float)(qq - 7);
                const float tt = fmaf(inv11 * gq, gq, fmaf(tpq, gq, tp));
                const float kv = __expf(-0.5f * tt);
                ksum += 2.0f * kv;
                conv = fmaf(kv, pa[qq] + pc[14 - qq], conv);
            }
        }
        out[OFF_PREPAN + tc] = conv / ksum;

        // finish sample + pre_msi
        float pm = xv[6];
#pragma unroll
        for (int ch = 0; ch < 4; ++ch) {
            const float v = w00 * m00[ch] + w01 * m01[ch] + w10 * m10[ch] + w11 * m11[ch];
            out[OFF_OMSI + (((b * 4) + ch) * CROPD + hh) * CROPD + ww] = v;
            pm = fmaf(v, xv[2 + ch], pm);
        }
        out[OFF_PREMSI + tc] = pm;
    }
}

extern "C" void kernel_launch(void* const* d_in, const int* in_sizes, int n_in,
                              void* d_out, int out_size, void* d_ws, size_t ws_size,
                              hipStream_t stream)
{
    const float* msi    = (const float*)d_in[0];
    const float* pan    = (const float*)d_in[1];
    const float* coords = (const float*)d_in[2];
    const float* w1  = (const float*)d_in[3];
    const float* b1  = (const float*)d_in[4];
    const float* w2  = (const float*)d_in[5];
    const float* b2  = (const float*)d_in[6];
    const float* wo  = (const float*)d_in[7];
    const float* bo  = (const float*)d_in[8];
    const float* wse = (const float*)d_in[9];
    const float* bse = (const float*)d_in[10];
    const float* wsa = (const float*)d_in[11];
    const float* bsa = (const float*)d_in[12];
    float* out = (float*)d_out;
    unsigned int* ws = (unsigned int*)d_ws;

    prep_kernel<<<(WS_NDW + 255) / 256, 256, 0, stream>>>(
        w1, b1, w2, b2, wo, bo, wse, bse, wsa, bsa, ws);
    fused_kernel<<<1024, 256, 0, stream>>>(coords, ws, pan, msi, out);
}